// Round 1
// baseline (1147.623 us; speedup 1.0000x reference)
//
#include <hip/hip_runtime.h>
#include <hip/hip_bf16.h>
#include <cstdint>
#include <cstddef>

// Problem constants (B=1 implicit)
static constexpr int kT   = 1024;
static constexpr int kCV  = 8;
static constexpr int kDim = 2048;
static constexpr int kNH  = 32;
static constexpr int kHD  = 64;
static constexpr int kW   = 8;

using bf16_t = __hip_bfloat16;

typedef __attribute__((ext_vector_type(8))) __bf16 bf16x8;
typedef __attribute__((ext_vector_type(4))) float  f32x4;

// ---------------------------------------------------------------------------
// fp32 -> bf16 cast, 8 elems/thread (all sizes are multiples of 8)
// ---------------------------------------------------------------------------
__global__ void cast_f32_to_bf16(const float* __restrict__ in,
                                 bf16_t* __restrict__ out, int n) {
    int i = (blockIdx.x * blockDim.x + threadIdx.x) * 8;
    if (i >= n) return;
    const float4 a = *reinterpret_cast<const float4*>(in + i);
    const float4 b = *reinterpret_cast<const float4*>(in + i + 4);
    union { bf16_t h[8]; uint4 u; } r;
    r.h[0] = __float2bfloat16(a.x); r.h[1] = __float2bfloat16(a.y);
    r.h[2] = __float2bfloat16(a.z); r.h[3] = __float2bfloat16(a.w);
    r.h[4] = __float2bfloat16(b.x); r.h[5] = __float2bfloat16(b.y);
    r.h[6] = __float2bfloat16(b.z); r.h[7] = __float2bfloat16(b.w);
    *reinterpret_cast<uint4*>(out + i) = r.u;
}

// ---------------------------------------------------------------------------
// GEMM: C[M,N] = A[M,K] * Wt[N,K]^T   (both operands K-contiguous, bf16)
// m97 structure: 128x128 tile, BK=32, 4 waves each 64x64 (4x4 MFMA tiles),
// global_load_lds width-16 staging (wave-uniform LDS base + lane*16).
// Requires M%128==0, N%128==0, K%32==0 (true for all our shapes).
// ---------------------------------------------------------------------------
template <bool OUT_BF16>
__global__ __launch_bounds__(256) void gemm_bt(const bf16_t* __restrict__ A,
                                               const bf16_t* __restrict__ Wt,
                                               void* __restrict__ Cout,
                                               int M, int N, int K) {
    __shared__ bf16_t As[128 * 32];   // 8 KB
    __shared__ bf16_t Bs[128 * 32];   // 8 KB

    const int tid  = threadIdx.x;
    const int wave = tid >> 6;
    const int lane = tid & 63;
    const int l16  = lane & 15;
    const int quad = lane >> 4;
    const int bm   = blockIdx.x * 128;
    const int bn   = blockIdx.y * 128;
    const int wm   = (wave >> 1) * 64;
    const int wn   = (wave & 1) * 64;

    f32x4 acc[4][4];
#pragma unroll
    for (int i = 0; i < 4; ++i)
#pragma unroll
        for (int j = 0; j < 4; ++j) acc[i][j] = (f32x4)0.0f;

    // Staging: 512 chunks of 16B per 8KB tile; thread tid handles chunk tid
    // (rows 0..63) and chunk tid+256 (rows 64..127).
    const int srow  = tid >> 2;        // 0..63
    const int skoff = (tid & 3) * 8;   // bf16 elems within the 32-wide K slab
    const bf16_t* gA0 = A  + (size_t)(bm + srow) * K + skoff;
    const bf16_t* gA1 = gA0 + (size_t)64 * K;
    const bf16_t* gB0 = Wt + (size_t)(bn + srow) * K + skoff;
    const bf16_t* gB1 = gB0 + (size_t)64 * K;
    // wave-uniform LDS dest bases (lane*16B is added by HW)
    bf16_t* lA0 = As + wave * 512;
    bf16_t* lA1 = As + 2048 + wave * 512;
    bf16_t* lB0 = Bs + wave * 512;
    bf16_t* lB1 = Bs + 2048 + wave * 512;

    for (int k0 = 0; k0 < K; k0 += 32) {
        __builtin_amdgcn_global_load_lds(
            (const __attribute__((address_space(1))) void*)(gA0 + k0),
            (__attribute__((address_space(3))) void*)lA0, 16, 0, 0);
        __builtin_amdgcn_global_load_lds(
            (const __attribute__((address_space(1))) void*)(gA1 + k0),
            (__attribute__((address_space(3))) void*)lA1, 16, 0, 0);
        __builtin_amdgcn_global_load_lds(
            (const __attribute__((address_space(1))) void*)(gB0 + k0),
            (__attribute__((address_space(3))) void*)lB0, 16, 0, 0);
        __builtin_amdgcn_global_load_lds(
            (const __attribute__((address_space(1))) void*)(gB1 + k0),
            (__attribute__((address_space(3))) void*)lB1, 16, 0, 0);
        __syncthreads();   // drains vmcnt -> staged data visible

        bf16x8 af[4], bfm[4];
#pragma unroll
        for (int i = 0; i < 4; ++i)
            af[i] = *reinterpret_cast<const bf16x8*>(
                &As[(wm + i * 16 + l16) * 32 + quad * 8]);
#pragma unroll
        for (int j = 0; j < 4; ++j)
            bfm[j] = *reinterpret_cast<const bf16x8*>(
                &Bs[(wn + j * 16 + l16) * 32 + quad * 8]);
#pragma unroll
        for (int i = 0; i < 4; ++i)
#pragma unroll
            for (int j = 0; j < 4; ++j)
                acc[i][j] = __builtin_amdgcn_mfma_f32_16x16x32_bf16(
                    af[i], bfm[j], acc[i][j], 0, 0, 0);
        __syncthreads();   // all waves done reading before next overwrite
    }

    // Epilogue. C/D layout: col = lane&15, row = quad*4 + reg  [verified m89]
#pragma unroll
    for (int i = 0; i < 4; ++i) {
#pragma unroll
        for (int rr = 0; rr < 4; ++rr) {
            const int row = bm + wm + i * 16 + quad * 4 + rr;
#pragma unroll
            for (int j = 0; j < 4; ++j) {
                const int col = bn + wn + j * 16 + l16;
                if constexpr (OUT_BF16) {
                    ((bf16_t*)Cout)[(size_t)row * N + col] =
                        __float2bfloat16(acc[i][j][rr]);
                } else {
                    ((float*)Cout)[(size_t)row * N + col] = acc[i][j][rr];
                }
            }
        }
    }
}

// ---------------------------------------------------------------------------
// Sliding-window attention. One wave per (t, head).
// RoPE is skipped: identical per-pair rotation of q and all keys at query
// time t (freqs[t] broadcast over the window axis) is orthogonal -> scores
// are mathematically unchanged; v is never roped.
// Zero-padded keys (t-7+w < 0) contribute score 0 (exp(0) in denominator)
// and v=0, matching the reference's zero-pad softmax semantics.
// ---------------------------------------------------------------------------
__global__ __launch_bounds__(64) void attn_kernel(
    const bf16_t* __restrict__ qb,   // [T, 2048]
    const bf16_t* __restrict__ kb,   // [T*CV, 2048], row = t*CV + c
    const bf16_t* __restrict__ vb,   // [T*CV, 2048]
    bf16_t* __restrict__ ob) {       // [T, 2048]
    const int t = blockIdx.x;
    const int h = blockIdx.y;
    const int d = threadIdx.x;       // 0..63

    __shared__ float kl[64][65];     // +1 pad: conflict-free column reads
    __shared__ float vl[64][65];
    __shared__ float ql[64];
    __shared__ float al[64];

    ql[d] = __bfloat162float(qb[(size_t)t * kDim + h * kHD + d]);

    // Stage 64 (w,c) key/value rows; kk = w*CV + c, source time = t-7+w.
#pragma unroll 4
    for (int kk = 0; kk < 64; ++kk) {
        const int w = kk >> 3, c = kk & 7;
        const int st = t - (kW - 1) + w;
        float kvv = 0.0f, vvv = 0.0f;
        if (st >= 0) {
            const size_t base = ((size_t)st * kCV + c) * kDim + h * kHD + d;
            kvv = __bfloat162float(kb[base]);
            vvv = __bfloat162float(vb[base]);
        }
        kl[kk][d] = kvv;
        vl[kk][d] = vvv;
    }
    __syncthreads();

    // Scores: lane = key index. Zero-padded rows give exactly s=0.
    const int kk = d;
    float s = 0.0f;
#pragma unroll
    for (int dd = 0; dd < 64; ++dd) s += ql[dd] * kl[kk][dd];
    s *= 0.125f;  // 1/sqrt(64)

    // Wave-wide softmax over the 64 scores.
    float m = s;
#pragma unroll
    for (int off = 32; off; off >>= 1) m = fmaxf(m, __shfl_xor(m, off));
    const float e = expf(s - m);
    float sum = e;
#pragma unroll
    for (int off = 32; off; off >>= 1) sum += __shfl_xor(sum, off);
    al[kk] = e / sum;
    __syncthreads();

    // Output: lane = dim. Padded v rows are zero -> no contribution.
    float o = 0.0f;
#pragma unroll
    for (int k2 = 0; k2 < 64; ++k2) o += al[k2] * vl[k2][d];
    ob[(size_t)t * kDim + h * kHD + d] = __float2bfloat16(o);
}

// ---------------------------------------------------------------------------
extern "C" void kernel_launch(void* const* d_in, const int* in_sizes, int n_in,
                              void* d_out, int out_size, void* d_ws,
                              size_t ws_size, hipStream_t stream) {
    const float* x     = (const float*)d_in[0];
    const float* chars = (const float*)d_in[1];
    const float* wq    = (const float*)d_in[2];
    const float* wk    = (const float*)d_in[3];
    const float* wv    = (const float*)d_in[4];
    const float* wo    = (const float*)d_in[5];
    float* out = (float*)d_out;

    // Workspace carve-up (all 256B-aligned by construction): ~140 MiB total.
    char* p = (char*)d_ws;
    bf16_t* xb  = (bf16_t*)p; p += (size_t)kT * kDim * 2;          // 4 MB
    bf16_t* cb  = (bf16_t*)p; p += (size_t)kT * kCV * kDim * 2;    // 32 MB
    bf16_t* wqb = (bf16_t*)p; p += (size_t)kDim * kDim * 2;        // 8 MB
    bf16_t* wkb = (bf16_t*)p; p += (size_t)kDim * kDim * 2;
    bf16_t* wvb = (bf16_t*)p; p += (size_t)kDim * kDim * 2;
    bf16_t* wob = (bf16_t*)p; p += (size_t)kDim * kDim * 2;
    bf16_t* qb  = (bf16_t*)p; p += (size_t)kT * kDim * 2;          // 4 MB
    bf16_t* kb  = (bf16_t*)p; p += (size_t)kT * kCV * kDim * 2;    // 32 MB
    bf16_t* vb  = (bf16_t*)p; p += (size_t)kT * kCV * kDim * 2;    // 32 MB
    bf16_t* ob  = (bf16_t*)p; p += (size_t)kT * kDim * 2;          // 4 MB

    auto cast = [&](const float* src, bf16_t* dst, int n) {
        cast_f32_to_bf16<<<dim3((n / 8 + 255) / 256), dim3(256), 0, stream>>>(
            src, dst, n);
    };
    cast(x, xb, kT * kDim);
    cast(chars, cb, kT * kCV * kDim);
    cast(wq, wqb, kDim * kDim);
    cast(wk, wkb, kDim * kDim);
    cast(wv, wvb, kDim * kDim);
    cast(wo, wob, kDim * kDim);

    // Projections (bf16 intermediates).
    gemm_bt<true><<<dim3(kT / 128, kDim / 128), 256, 0, stream>>>(
        xb, wqb, qb, kT, kDim, kDim);
    gemm_bt<true><<<dim3(kT * kCV / 128, kDim / 128), 256, 0, stream>>>(
        cb, wkb, kb, kT * kCV, kDim, kDim);
    gemm_bt<true><<<dim3(kT * kCV / 128, kDim / 128), 256, 0, stream>>>(
        cb, wvb, vb, kT * kCV, kDim, kDim);

    // Sliding-window attention (RoPE skipped — exact cancellation).
    attn_kernel<<<dim3(kT, kNH), 64, 0, stream>>>(qb, kb, vb, ob);

    // Output projection (fp32 out).
    gemm_bt<false><<<dim3(kT / 128, kDim / 128), 256, 0, stream>>>(
        ob, wob, out, kT, kDim, kDim);
}

// Round 2
// 498.336 us; speedup vs baseline: 2.3029x; 2.3029x over previous
//
#include <hip/hip_runtime.h>
#include <hip/hip_bf16.h>
#include <cstdint>
#include <cstddef>

// Problem constants (B=1 implicit)
static constexpr int kT   = 1024;
static constexpr int kCV  = 8;
static constexpr int kDim = 2048;
static constexpr int kNH  = 32;
static constexpr int kHD  = 64;
static constexpr int kW   = 8;

using bf16_t = __hip_bfloat16;

typedef __attribute__((ext_vector_type(8))) __bf16 bf16x8;
typedef __attribute__((ext_vector_type(4))) float  f32x4;

__device__ __forceinline__ float bf_bits_to_f32(unsigned short u) {
    union { unsigned int i; float f; } c;
    c.i = ((unsigned int)u) << 16;
    return c.f;
}

// ---------------------------------------------------------------------------
// fp32 -> bf16 cast, 8 elems/thread (all sizes are multiples of 8)
// ---------------------------------------------------------------------------
__global__ void cast_f32_to_bf16(const float* __restrict__ in,
                                 bf16_t* __restrict__ out, int n) {
    int i = (blockIdx.x * blockDim.x + threadIdx.x) * 8;
    if (i >= n) return;
    const float4 a = *reinterpret_cast<const float4*>(in + i);
    const float4 b = *reinterpret_cast<const float4*>(in + i + 4);
    union { bf16_t h[8]; uint4 u; } r;
    r.h[0] = __float2bfloat16(a.x); r.h[1] = __float2bfloat16(a.y);
    r.h[2] = __float2bfloat16(a.z); r.h[3] = __float2bfloat16(a.w);
    r.h[4] = __float2bfloat16(b.x); r.h[5] = __float2bfloat16(b.y);
    r.h[6] = __float2bfloat16(b.z); r.h[7] = __float2bfloat16(b.w);
    *reinterpret_cast<uint4*>(out + i) = r.u;
}

// ---------------------------------------------------------------------------
// GEMM: C[M,N] = A[M,K] * Wt[N,K]^T   (both operands K-contiguous, bf16)
// m97 structure: 128x128 tile, BK=32, 4 waves each 64x64 (4x4 MFMA tiles),
// global_load_lds width-16 staging (wave-uniform LDS base + lane*16).
// ---------------------------------------------------------------------------
template <bool OUT_BF16>
__global__ __launch_bounds__(256) void gemm_bt(const bf16_t* __restrict__ A,
                                               const bf16_t* __restrict__ Wt,
                                               void* __restrict__ Cout,
                                               int M, int N, int K) {
    __shared__ bf16_t As[128 * 32];   // 8 KB
    __shared__ bf16_t Bs[128 * 32];   // 8 KB

    const int tid  = threadIdx.x;
    const int wave = tid >> 6;
    const int lane = tid & 63;
    const int l16  = lane & 15;
    const int quad = lane >> 4;
    const int bm   = blockIdx.x * 128;
    const int bn   = blockIdx.y * 128;
    const int wm   = (wave >> 1) * 64;
    const int wn   = (wave & 1) * 64;

    f32x4 acc[4][4];
#pragma unroll
    for (int i = 0; i < 4; ++i)
#pragma unroll
        for (int j = 0; j < 4; ++j) acc[i][j] = (f32x4)0.0f;

    const int srow  = tid >> 2;        // 0..63
    const int skoff = (tid & 3) * 8;   // bf16 elems within the 32-wide K slab
    const bf16_t* gA0 = A  + (size_t)(bm + srow) * K + skoff;
    const bf16_t* gA1 = gA0 + (size_t)64 * K;
    const bf16_t* gB0 = Wt + (size_t)(bn + srow) * K + skoff;
    const bf16_t* gB1 = gB0 + (size_t)64 * K;
    bf16_t* lA0 = As + wave * 512;
    bf16_t* lA1 = As + 2048 + wave * 512;
    bf16_t* lB0 = Bs + wave * 512;
    bf16_t* lB1 = Bs + 2048 + wave * 512;

    for (int k0 = 0; k0 < K; k0 += 32) {
        __builtin_amdgcn_global_load_lds(
            (const __attribute__((address_space(1))) void*)(gA0 + k0),
            (__attribute__((address_space(3))) void*)lA0, 16, 0, 0);
        __builtin_amdgcn_global_load_lds(
            (const __attribute__((address_space(1))) void*)(gA1 + k0),
            (__attribute__((address_space(3))) void*)lA1, 16, 0, 0);
        __builtin_amdgcn_global_load_lds(
            (const __attribute__((address_space(1))) void*)(gB0 + k0),
            (__attribute__((address_space(3))) void*)lB0, 16, 0, 0);
        __builtin_amdgcn_global_load_lds(
            (const __attribute__((address_space(1))) void*)(gB1 + k0),
            (__attribute__((address_space(3))) void*)lB1, 16, 0, 0);
        __syncthreads();

        bf16x8 af[4], bfm[4];
#pragma unroll
        for (int i = 0; i < 4; ++i)
            af[i] = *reinterpret_cast<const bf16x8*>(
                &As[(wm + i * 16 + l16) * 32 + quad * 8]);
#pragma unroll
        for (int j = 0; j < 4; ++j)
            bfm[j] = *reinterpret_cast<const bf16x8*>(
                &Bs[(wn + j * 16 + l16) * 32 + quad * 8]);
#pragma unroll
        for (int i = 0; i < 4; ++i)
#pragma unroll
            for (int j = 0; j < 4; ++j)
                acc[i][j] = __builtin_amdgcn_mfma_f32_16x16x32_bf16(
                    af[i], bfm[j], acc[i][j], 0, 0, 0);
        __syncthreads();
    }

    // Epilogue. C/D layout: col = lane&15, row = quad*4 + reg  [verified m89]
#pragma unroll
    for (int i = 0; i < 4; ++i) {
#pragma unroll
        for (int rr = 0; rr < 4; ++rr) {
            const int row = bm + wm + i * 16 + quad * 4 + rr;
#pragma unroll
            for (int j = 0; j < 4; ++j) {
                const int col = bn + wn + j * 16 + l16;
                if constexpr (OUT_BF16) {
                    ((bf16_t*)Cout)[(size_t)row * N + col] =
                        __float2bfloat16(acc[i][j][rr]);
                } else {
                    ((float*)Cout)[(size_t)row * N + col] = acc[i][j][rr];
                }
            }
        }
    }
}

// ---------------------------------------------------------------------------
// Sliding-window attention, tiled for occupancy + reuse.
// Block = 1024 threads = 16 waves; wave w handles query t = t0 + w of head h.
// k/v rows for source times [t0-7, t0+15] (23 x CV = 184 rows) staged ONCE in
// bf16 LDS (padded stride 72 keeps 16B alignment; conflicts <= 8-way on the
// tiny score loop, 2-way (free) on PV).
// RoPE skipped: q and all its window keys get the identical per-pair rotation
// (freqs[t] broadcast over window axis) -> dot products unchanged. Zero-padded
// keys give score exactly 0 (exp(0) in denom) and v=0, matching reference.
// ---------------------------------------------------------------------------
static constexpr int kTT   = 16;              // query positions per block
static constexpr int kSRC  = kTT + kW - 1;    // 23 source times
static constexpr int kROWS = kSRC * kCV;      // 184 staged rows
static constexpr int kLDK  = 72;              // padded row stride (bf16 elems)

__global__ __launch_bounds__(1024) void attn_kernel(
    const bf16_t* __restrict__ qb,   // [T, 2048]
    const bf16_t* __restrict__ kb,   // [T*CV, 2048], row = t*CV + c
    const bf16_t* __restrict__ vb,   // [T*CV, 2048]
    bf16_t* __restrict__ ob) {       // [T, 2048]
    __shared__ unsigned short kl[kROWS * kLDK];   // 25.9 KB
    __shared__ unsigned short vl[kROWS * kLDK];   // 25.9 KB
    __shared__ float ql[kTT * 64];                // 4 KB
    __shared__ float al[kTT * 64];                // 4 KB

    const int t0   = blockIdx.x * kTT;
    const int h    = blockIdx.y;
    const int tid  = threadIdx.x;
    const int wave = tid >> 6;       // 0..15 == local t
    const int lane = tid & 63;

    // Stage q (one row per wave, lane = dim).
    ql[tid] = __bfloat162float(qb[(size_t)(t0 + wave) * kDim + h * kHD + lane]);

    // Stage k/v: kROWS*8 = 1472 16B-chunks each; thread handles chunks
    // tid and tid+1024. Global row for staged row r is (t0-7)*CV + r (linear!).
    const long long grow0 = (long long)(t0 - (kW - 1)) * kCV;
#pragma unroll
    for (int c = tid; c < kROWS * 8; c += 1024) {
        const int r   = c >> 3;
        const int sub = c & 7;
        const long long grow = grow0 + r;       // = srcTime*CV + cv
        uint4 kd = make_uint4(0, 0, 0, 0), vd = make_uint4(0, 0, 0, 0);
        if (grow >= 0) {
            const size_t gb = (size_t)grow * kDim + h * kHD + sub * 8;
            kd = *reinterpret_cast<const uint4*>(kb + gb);
            vd = *reinterpret_cast<const uint4*>(vb + gb);
        }
        *reinterpret_cast<uint4*>(&kl[r * kLDK + sub * 8]) = kd;
        *reinterpret_cast<uint4*>(&vl[r * kLDK + sub * 8]) = vd;
    }
    __syncthreads();

    // ---- Scores: lane = key index kk = w*CV + cv -> staged row wave*8 + kk.
    const int r = wave * kCV + lane;  // (wave + (kk>>3))*8 + (kk&7) = wave*8+kk
    float s = 0.0f;
#pragma unroll
    for (int c = 0; c < 8; ++c) {
        union { uint4 u; unsigned short us[8]; } kv;
        kv.u = *reinterpret_cast<const uint4*>(&kl[r * kLDK + c * 8]);
        const float4 qa = *reinterpret_cast<const float4*>(&ql[wave * 64 + c * 8]);
        const float4 qc = *reinterpret_cast<const float4*>(&ql[wave * 64 + c * 8 + 4]);
        s += bf_bits_to_f32(kv.us[0]) * qa.x + bf_bits_to_f32(kv.us[1]) * qa.y +
             bf_bits_to_f32(kv.us[2]) * qa.z + bf_bits_to_f32(kv.us[3]) * qa.w +
             bf_bits_to_f32(kv.us[4]) * qc.x + bf_bits_to_f32(kv.us[5]) * qc.y +
             bf_bits_to_f32(kv.us[6]) * qc.z + bf_bits_to_f32(kv.us[7]) * qc.w;
    }
    s *= 0.125f;  // 1/sqrt(64)

    // Wave-wide softmax over the 64 scores (zero-padded keys give s=0).
    float m = s;
#pragma unroll
    for (int off = 32; off; off >>= 1) m = fmaxf(m, __shfl_xor(m, off));
    const float e = __expf(s - m);
    float sum = e;
#pragma unroll
    for (int off = 32; off; off >>= 1) sum += __shfl_xor(sum, off);
    al[wave * 64 + lane] = e / sum;   // same-wave write/read: no barrier needed

    // ---- PV: lane = dim d. Rows re-walk the banded window; al broadcast.
    float o = 0.0f;
#pragma unroll
    for (int k2 = 0; k2 < 64; ++k2) {
        const int r2 = wave * kCV + k2;   // staged row for key k2
        o += al[wave * 64 + k2] * bf_bits_to_f32(vl[r2 * kLDK + lane]);
    }
    ob[(size_t)(t0 + wave) * kDim + h * kHD + lane] = __float2bfloat16(o);
}

// ---------------------------------------------------------------------------
extern "C" void kernel_launch(void* const* d_in, const int* in_sizes, int n_in,
                              void* d_out, int out_size, void* d_ws,
                              size_t ws_size, hipStream_t stream) {
    const float* x     = (const float*)d_in[0];
    const float* chars = (const float*)d_in[1];
    const float* wq    = (const float*)d_in[2];
    const float* wk    = (const float*)d_in[3];
    const float* wv    = (const float*)d_in[4];
    const float* wo    = (const float*)d_in[5];
    float* out = (float*)d_out;

    // Workspace carve-up (~140 MiB total).
    char* p = (char*)d_ws;
    bf16_t* xb  = (bf16_t*)p; p += (size_t)kT * kDim * 2;          // 4 MB
    bf16_t* cb  = (bf16_t*)p; p += (size_t)kT * kCV * kDim * 2;    // 32 MB
    bf16_t* wqb = (bf16_t*)p; p += (size_t)kDim * kDim * 2;        // 8 MB
    bf16_t* wkb = (bf16_t*)p; p += (size_t)kDim * kDim * 2;
    bf16_t* wvb = (bf16_t*)p; p += (size_t)kDim * kDim * 2;
    bf16_t* wob = (bf16_t*)p; p += (size_t)kDim * kDim * 2;
    bf16_t* qb  = (bf16_t*)p; p += (size_t)kT * kDim * 2;          // 4 MB
    bf16_t* kb  = (bf16_t*)p; p += (size_t)kT * kCV * kDim * 2;    // 32 MB
    bf16_t* vb  = (bf16_t*)p; p += (size_t)kT * kCV * kDim * 2;    // 32 MB
    bf16_t* ob  = (bf16_t*)p; p += (size_t)kT * kDim * 2;          // 4 MB

    auto cast = [&](const float* src, bf16_t* dst, int n) {
        cast_f32_to_bf16<<<dim3((n / 8 + 255) / 256), dim3(256), 0, stream>>>(
            src, dst, n);
    };
    cast(x, xb, kT * kDim);
    cast(chars, cb, kT * kCV * kDim);
    cast(wq, wqb, kDim * kDim);
    cast(wk, wkb, kDim * kDim);
    cast(wv, wvb, kDim * kDim);
    cast(wo, wob, kDim * kDim);

    // Projections (bf16 intermediates).
    gemm_bt<true><<<dim3(kT / 128, kDim / 128), 256, 0, stream>>>(
        xb, wqb, qb, kT, kDim, kDim);
    gemm_bt<true><<<dim3(kT * kCV / 128, kDim / 128), 256, 0, stream>>>(
        cb, wkb, kb, kT * kCV, kDim, kDim);
    gemm_bt<true><<<dim3(kT * kCV / 128, kDim / 128), 256, 0, stream>>>(
        cb, wvb, vb, kT * kCV, kDim, kDim);

    // Sliding-window attention (RoPE skipped — exact cancellation).
    attn_kernel<<<dim3(kT / kTT, kNH), 1024, 0, stream>>>(qb, kb, vb, ob);

    // Output projection (fp32 out).
    gemm_bt<false><<<dim3(kT / 128, kDim / 128), 256, 0, stream>>>(
        ob, wob, out, kT, kDim, kDim);
}

// Round 3
// 360.505 us; speedup vs baseline: 3.1834x; 1.3823x over previous
//
#include <hip/hip_runtime.h>
#include <hip/hip_bf16.h>
#include <cstdint>
#include <cstddef>

// Problem constants (B=1 implicit)
static constexpr int kT   = 1024;
static constexpr int kCV  = 8;
static constexpr int kDim = 2048;
static constexpr int kNH  = 32;
static constexpr int kHD  = 64;
static constexpr int kW   = 8;
static constexpr int kK   = 2048;   // inner dim of every GEMM

using bf16_t = __hip_bfloat16;

typedef __attribute__((ext_vector_type(8))) __bf16 bf16x8;
typedef __attribute__((ext_vector_type(4))) float  f32x4;

__device__ __forceinline__ float bf_bits_to_f32(unsigned short u) {
    union { unsigned int i; float f; } c;
    c.i = ((unsigned int)u) << 16;
    return c.f;
}

// ---------------------------------------------------------------------------
// Merged fp32 -> bf16 cast for all 6 inputs in ONE launch.
// ---------------------------------------------------------------------------
struct CastArgs {
    const float* src[6];
    bf16_t*      dst[6];
    int          cum[7];   // cumulative 8-elem chunk counts
};

__global__ void cast_all(CastArgs a, int total_chunks) {
    const int c = blockIdx.x * blockDim.x + threadIdx.x;
    if (c >= total_chunks) return;
    int r = 0;
#pragma unroll
    for (int i = 1; i <= 5; ++i) r += (c >= a.cum[i]) ? 1 : 0;
    const int local = c - a.cum[r];
    const float* s = a.src[r] + (size_t)local * 8;
    bf16_t*      d = a.dst[r] + (size_t)local * 8;
    const float4 lo = *reinterpret_cast<const float4*>(s);
    const float4 hi = *reinterpret_cast<const float4*>(s + 4);
    union { bf16_t h[8]; uint4 u; } o;
    o.h[0] = __float2bfloat16(lo.x); o.h[1] = __float2bfloat16(lo.y);
    o.h[2] = __float2bfloat16(lo.z); o.h[3] = __float2bfloat16(lo.w);
    o.h[4] = __float2bfloat16(hi.x); o.h[5] = __float2bfloat16(hi.y);
    o.h[6] = __float2bfloat16(hi.z); o.h[7] = __float2bfloat16(hi.w);
    *reinterpret_cast<uint4*>(d) = o.u;
}

// ---------------------------------------------------------------------------
// GEMM body: C[128x128 tile] = A[M,K] * Wt[N,K]^T, bf16 in, K = 2048, BK=64.
// XOR-swizzled LDS: staging loads global chunk j^(row&7) into LDS slot j, so
// fragment ds_read_b128s hit all 32 banks 2-way (free) instead of 8-way.
// global_load_lds stays lane-linear on the LDS side (m104 constraint) and the
// permutation is within one 128B row segment -> coalescing preserved.
// BK=64: 32 MFMA per barrier pair (halved barrier count vs BK=32).
// ---------------------------------------------------------------------------
template <bool OUT_BF16, typename CT>
__device__ __forceinline__ void gemm_body(const bf16_t* __restrict__ A,
                                          const bf16_t* __restrict__ Wt,
                                          CT* __restrict__ C,
                                          int bm, int bn, int ldc) {
    __shared__ bf16_t As[128 * 64];   // 16 KB
    __shared__ bf16_t Bs[128 * 64];   // 16 KB

    const int tid  = threadIdx.x;
    const int wave = tid >> 6;
    const int lane = tid & 63;
    const int l16  = lane & 15;
    const int quad = lane >> 4;
    const int wm   = (wave >> 1) * 64;
    const int wn   = (wave & 1) * 64;

    f32x4 acc[4][4];
#pragma unroll
    for (int i = 0; i < 4; ++i)
#pragma unroll
        for (int j = 0; j < 4; ++j) acc[i][j] = (f32x4)0.0f;

    // Staging map: LDS chunk c = i*256 + tid (i = 0..3), row = c>>3 (0..127),
    // LDS slot-in-row jl = c&7. Global chunk j_g = jl ^ (row&7); row&7 is
    // (tid>>3)&7 for every i (i*32 = 0 mod 8), so one base pointer suffices.
    const int srow = tid >> 3;                       // 0..31
    const int jg   = (tid & 7) ^ (srow & 7);
    const bf16_t* gA = A  + (size_t)(bm + srow) * kK + jg * 8;
    const bf16_t* gB = Wt + (size_t)(bn + srow) * kK + jg * 8;

    for (int k0 = 0; k0 < kK; k0 += 64) {
#pragma unroll
        for (int i = 0; i < 4; ++i) {
            __builtin_amdgcn_global_load_lds(
                (const __attribute__((address_space(1))) void*)(gA + (size_t)i * 32 * kK + k0),
                (__attribute__((address_space(3))) void*)(As + i * 2048 + wave * 512),
                16, 0, 0);
            __builtin_amdgcn_global_load_lds(
                (const __attribute__((address_space(1))) void*)(gB + (size_t)i * 32 * kK + k0),
                (__attribute__((address_space(3))) void*)(Bs + i * 2048 + wave * 512),
                16, 0, 0);
        }
        __syncthreads();

#pragma unroll
        for (int ph = 0; ph < 2; ++ph) {
            bf16x8 af[4], bfr[4];
#pragma unroll
            for (int i = 0; i < 4; ++i) {
                const int jla = (ph * 4 + quad) ^ (l16 & 7);   // swizzled slot
                af[i]  = *reinterpret_cast<const bf16x8*>(
                    &As[(wm + i * 16 + l16) * 64 + jla * 8]);
                bfr[i] = *reinterpret_cast<const bf16x8*>(
                    &Bs[(wn + i * 16 + l16) * 64 + jla * 8]);
            }
#pragma unroll
            for (int i = 0; i < 4; ++i)
#pragma unroll
                for (int j = 0; j < 4; ++j)
                    acc[i][j] = __builtin_amdgcn_mfma_f32_16x16x32_bf16(
                        af[i], bfr[j], acc[i][j], 0, 0, 0);
        }
        __syncthreads();
    }

    // Epilogue. C/D layout: col = lane&15, row = quad*4 + reg  [m89]
#pragma unroll
    for (int i = 0; i < 4; ++i) {
#pragma unroll
        for (int rr = 0; rr < 4; ++rr) {
            const int row = bm + wm + i * 16 + quad * 4 + rr;
#pragma unroll
            for (int j = 0; j < 4; ++j) {
                const int col = bn + wn + j * 16 + l16;
                if constexpr (OUT_BF16) {
                    C[(size_t)row * ldc + col] = __float2bfloat16(acc[i][j][rr]);
                } else {
                    C[(size_t)row * ldc + col] = acc[i][j][rr];
                }
            }
        }
    }
}

// ---------------------------------------------------------------------------
// Fused projection kernel: blocks 0..2047 compute kv = chars @ [wk|wv]^T
// (N=4096, interleaved kvb[8192][4096]: cols 0..2047 = k, 2048.. = v);
// blocks 2048..2175 compute q = x @ wq^T. One launch saturates all CUs.
// ---------------------------------------------------------------------------
__global__ __launch_bounds__(256, 3) void proj_kernel(
    const bf16_t* __restrict__ xb, const bf16_t* __restrict__ cb,
    const bf16_t* __restrict__ wqb, const bf16_t* __restrict__ wkvb,
    bf16_t* __restrict__ qb, bf16_t* __restrict__ kvb) {
    const int bid = blockIdx.x;
    if (bid < 2048) {
        const int bm = (bid >> 5) * 128;   // 64 M-tiles (8192 rows)
        const int bn = (bid & 31) * 128;   // 32 N-tiles (N = 4096)
        gemm_body<true>(cb, wkvb, kvb, bm, bn, 4096);
    } else {
        const int t  = bid - 2048;
        const int bm = (t >> 4) * 128;     // 8 M-tiles (1024 rows)
        const int bn = (t & 15) * 128;     // 16 N-tiles (N = 2048)
        gemm_body<true>(xb, wqb, qb, bm, bn, 2048);
    }
}

// Output projection: out[1024,2048] = attn_out @ wo^T (fp32 out).
__global__ __launch_bounds__(256, 3) void out_gemm(
    const bf16_t* __restrict__ ob, const bf16_t* __restrict__ wob,
    float* __restrict__ out) {
    const int bm = (blockIdx.x >> 4) * 128;
    const int bn = (blockIdx.x & 15) * 128;
    gemm_body<false>(ob, wob, out, bm, bn, 2048);
}

// ---------------------------------------------------------------------------
// Sliding-window attention (unchanged structure from R2; kvb is interleaved).
// Block = 16 waves; wave w handles query t0+w of head h. 184 k/v rows staged
// once per block. RoPE skipped (exact cancellation: q and all its window keys
// share the per-pair rotation angle). Zero-padded keys -> score exactly 0.
// ---------------------------------------------------------------------------
static constexpr int kTT   = 16;
static constexpr int kSRC  = kTT + kW - 1;    // 23 source times
static constexpr int kROWS = kSRC * kCV;      // 184 staged rows
static constexpr int kLDK  = 72;              // padded row stride (bf16)

__global__ __launch_bounds__(1024) void attn_kernel(
    const bf16_t* __restrict__ qb,    // [T, 2048]
    const bf16_t* __restrict__ kvb,   // [T*CV, 4096]: [:,0:2048]=k [:,2048:]=v
    bf16_t* __restrict__ ob) {        // [T, 2048]
    __shared__ unsigned short kl[kROWS * kLDK];   // 25.9 KB
    __shared__ unsigned short vl[kROWS * kLDK];   // 25.9 KB
    __shared__ float ql[kTT * 64];                // 4 KB
    __shared__ float al[kTT * 64];                // 4 KB

    const int t0   = blockIdx.x * kTT;
    const int h    = blockIdx.y;
    const int tid  = threadIdx.x;
    const int wave = tid >> 6;
    const int lane = tid & 63;

    ql[tid] = __bfloat162float(qb[(size_t)(t0 + wave) * kDim + h * kHD + lane]);

    const long long grow0 = (long long)(t0 - (kW - 1)) * kCV;
#pragma unroll
    for (int c = tid; c < kROWS * 8; c += 1024) {
        const int r   = c >> 3;
        const int sub = c & 7;
        const long long grow = grow0 + r;
        uint4 kd = make_uint4(0, 0, 0, 0), vd = make_uint4(0, 0, 0, 0);
        if (grow >= 0) {
            const size_t gb = (size_t)grow * 4096 + h * kHD + sub * 8;
            kd = *reinterpret_cast<const uint4*>(kvb + gb);
            vd = *reinterpret_cast<const uint4*>(kvb + gb + 2048);
        }
        *reinterpret_cast<uint4*>(&kl[r * kLDK + sub * 8]) = kd;
        *reinterpret_cast<uint4*>(&vl[r * kLDK + sub * 8]) = vd;
    }
    __syncthreads();

    // Scores: lane = key kk = w*CV+cv -> staged row wave*8 + kk.
    const int r = wave * kCV + lane;
    float s = 0.0f;
#pragma unroll
    for (int c = 0; c < 8; ++c) {
        union { uint4 u; unsigned short us[8]; } kv;
        kv.u = *reinterpret_cast<const uint4*>(&kl[r * kLDK + c * 8]);
        const float4 qa = *reinterpret_cast<const float4*>(&ql[wave * 64 + c * 8]);
        const float4 qc = *reinterpret_cast<const float4*>(&ql[wave * 64 + c * 8 + 4]);
        s += bf_bits_to_f32(kv.us[0]) * qa.x + bf_bits_to_f32(kv.us[1]) * qa.y +
             bf_bits_to_f32(kv.us[2]) * qa.z + bf_bits_to_f32(kv.us[3]) * qa.w +
             bf_bits_to_f32(kv.us[4]) * qc.x + bf_bits_to_f32(kv.us[5]) * qc.y +
             bf_bits_to_f32(kv.us[6]) * qc.z + bf_bits_to_f32(kv.us[7]) * qc.w;
    }
    s *= 0.125f;

    float m = s;
#pragma unroll
    for (int off = 32; off; off >>= 1) m = fmaxf(m, __shfl_xor(m, off));
    const float e = __expf(s - m);
    float sum = e;
#pragma unroll
    for (int off = 32; off; off >>= 1) sum += __shfl_xor(sum, off);
    al[wave * 64 + lane] = e / sum;   // same-wave producer/consumer

    float o = 0.0f;
#pragma unroll
    for (int k2 = 0; k2 < 64; ++k2)
        o += al[wave * 64 + k2] * bf_bits_to_f32(vl[(wave * kCV + k2) * kLDK + lane]);
    ob[(size_t)(t0 + wave) * kDim + h * kHD + lane] = __float2bfloat16(o);
}

// ---------------------------------------------------------------------------
extern "C" void kernel_launch(void* const* d_in, const int* in_sizes, int n_in,
                              void* d_out, int out_size, void* d_ws,
                              size_t ws_size, hipStream_t stream) {
    const float* x     = (const float*)d_in[0];
    const float* chars = (const float*)d_in[1];
    const float* wq    = (const float*)d_in[2];
    const float* wk    = (const float*)d_in[3];
    const float* wv    = (const float*)d_in[4];
    const float* wo    = (const float*)d_in[5];
    float* out = (float*)d_out;

    // Workspace carve-up (~140 MiB total).
    char* p = (char*)d_ws;
    bf16_t* xb   = (bf16_t*)p; p += (size_t)kT * kDim * 2;            // 4 MB
    bf16_t* cb   = (bf16_t*)p; p += (size_t)kT * kCV * kDim * 2;      // 32 MB
    bf16_t* wqb  = (bf16_t*)p; p += (size_t)kDim * kDim * 2;          // 8 MB
    bf16_t* wkvb = (bf16_t*)p; p += (size_t)2 * kDim * kDim * 2;      // 16 MB
    bf16_t* wob  = (bf16_t*)p; p += (size_t)kDim * kDim * 2;          // 8 MB
    bf16_t* qb   = (bf16_t*)p; p += (size_t)kT * kDim * 2;            // 4 MB
    bf16_t* kvb  = (bf16_t*)p; p += (size_t)kT * kCV * 2 * kDim * 2;  // 64 MB
    bf16_t* ob   = (bf16_t*)p; p += (size_t)kT * kDim * 2;            // 4 MB

    // One cast launch for all six tensors.
    CastArgs ca;
    ca.src[0] = x;     ca.dst[0] = xb;
    ca.src[1] = chars; ca.dst[1] = cb;
    ca.src[2] = wq;    ca.dst[2] = wqb;
    ca.src[3] = wk;    ca.dst[3] = wkvb;                  // rows 0..2047
    ca.src[4] = wv;    ca.dst[4] = wkvb + (size_t)kDim * kDim;  // rows 2048..
    ca.src[5] = wo;    ca.dst[5] = wob;
    const int sizes[6] = {kT * kDim, kT * kCV * kDim, kDim * kDim,
                          kDim * kDim, kDim * kDim, kDim * kDim};
    int cum = 0;
    ca.cum[0] = 0;
    for (int i = 0; i < 6; ++i) { cum += sizes[i] / 8; ca.cum[i + 1] = cum; }
    cast_all<<<dim3((cum + 255) / 256), dim3(256), 0, stream>>>(ca, cum);

    // Fused k|v (N=4096) + q projections: 2048 + 128 blocks, one launch.
    proj_kernel<<<dim3(2176), dim3(256), 0, stream>>>(xb, cb, wqb, wkvb, qb, kvb);

    // Sliding-window attention.
    attn_kernel<<<dim3(kT / kTT, kNH), dim3(1024), 0, stream>>>(qb, kvb, ob);

    // Output projection (fp32 out).
    out_gemm<<<dim3(128), dim3(256), 0, stream>>>(ob, wob, out);
}